// Round 2
// baseline (1355.237 us; speedup 1.0000x reference)
//
#include <hip/hip_runtime.h>
#include <hip/hip_bf16.h>

#define HC  256   // H * C (heads * per-head channels)
#define FIN 32    // input feature dim of each GAT layer
#define NH  8     // heads

// ---------------- CSR build (dst is identical for both layers) ----------------
__global__ void count_kernel(const int* __restrict__ dst, int* __restrict__ cnt, int E_) {
  int e = blockIdx.x * blockDim.x + threadIdx.x;
  if (e < E_) atomicAdd(&cnt[dst[e]], 1);
}

__global__ void scan_kernel(const int* __restrict__ cnt, int* __restrict__ rowptr,
                            int* __restrict__ fill, int N_, int E_) {
  __shared__ int part[1024];
  int t = threadIdx.x;
  int chunk = (N_ + 1023) / 1024;
  int lo = t * chunk, hi = lo + chunk;
  if (lo > N_) lo = N_;
  if (hi > N_) hi = N_;
  int s = 0;
  for (int i = lo; i < hi; ++i) s += cnt[i];
  part[t] = s;
  __syncthreads();
  if (t == 0) {
    int run = 0;
    for (int i = 0; i < 1024; ++i) { int v = part[i]; part[i] = run; run += v; }
  }
  __syncthreads();
  int run = part[t];
  for (int i = lo; i < hi; ++i) { rowptr[i] = run; fill[i] = run; run += cnt[i]; }
  if (t == 0) rowptr[N_] = E_;
}

__global__ void scatter_kernel(const int* __restrict__ dst, int* __restrict__ fill,
                               int* __restrict__ perm, int E_) {
  int e = blockIdx.x * blockDim.x + threadIdx.x;
  if (e < E_) {
    int pos = atomicAdd(&fill[dst[e]], 1);
    perm[pos] = e;
  }
}

// ---------------- fold We[8,256] x a_e[8,32] -> M[8,8] for both layers --------
__global__ void fold_kernel(const float* __restrict__ We1, const float* __restrict__ ae1,
                            const float* __restrict__ We2, const float* __restrict__ ae2,
                            float* __restrict__ M) {
  int t = threadIdx.x;             // 0..127
  const float* We = (t < 64) ? We1 : We2;
  const float* ae = (t < 64) ? ae1 : ae2;
  int i = t & 63;
  int k = i >> 3, hh = i & 7;
  float s = 0.f;
  for (int c = 0; c < FIN; ++c)
    s = fmaf(We[k * HC + hh * FIN + c], ae[hh * FIN + c], s);
  M[t] = s;                        // M[layer*64 + k*8 + hh]
}

// ---------------- h = x@W  (+ per-head attention logits) ---------------------
__global__ void node_kernel(const float* __restrict__ emb, const int* __restrict__ node_ids,
                            const float* __restrict__ xin,
                            const float* __restrict__ W,
                            const float* __restrict__ a_src, const float* __restrict__ a_dst,
                            float* __restrict__ h, float* __restrict__ alsrc,
                            float* __restrict__ aldst) {
  int n = blockIdx.x, t = threadIdx.x;
  __shared__ float xs[FIN];
  __shared__ float red[HC];
  if (t < FIN) {
    if (node_ids) xs[t] = emb[(size_t)node_ids[n] * FIN + t];
    else          xs[t] = xin[n * FIN + t];
  }
  __syncthreads();
  float acc = 0.f;
#pragma unroll
  for (int k = 0; k < FIN; ++k) acc = fmaf(xs[k], W[k * HC + t], acc);
  h[(size_t)n * HC + t] = acc;

  red[t] = acc * a_src[t];
  __syncthreads();
  if (t < NH) {
    float s = 0.f;
    for (int c = 0; c < FIN; ++c) s += red[t * FIN + c];
    alsrc[n * NH + t] = s;
  }
  __syncthreads();
  red[t] = acc * a_dst[t];
  __syncthreads();
  if (t < NH) {
    float s = 0.f;
    for (int c = 0; c < FIN; ++c) s += red[t * FIN + c];
    aldst[n * NH + t] = s;
  }
}

// ---------------- per-edge: ex = exp(leaky_relu(alpha)) ----------------------
__global__ void edge_kernel(const int* __restrict__ src, const int* __restrict__ dst,
                            const float* __restrict__ edge_attr, const float* __restrict__ M,
                            const float* __restrict__ alsrc, const float* __restrict__ aldst,
                            float* __restrict__ ex, int E_) {
  int e = blockIdx.x * blockDim.x + threadIdx.x;
  if (e >= E_) return;
  float ea[NH];
#pragma unroll
  for (int k = 0; k < NH; ++k) ea[k] = edge_attr[e * NH + k];
  int s = src[e], d = dst[e];
#pragma unroll
  for (int hh = 0; hh < NH; ++hh) {
    float al = 0.f;
#pragma unroll
    for (int k = 0; k < NH; ++k) al = fmaf(ea[k], M[k * NH + hh], al);
    float a = alsrc[s * NH + hh] + aldst[d * NH + hh] + al;
    a = (a >= 0.f) ? a : 0.2f * a;     // leaky_relu, slope 0.2
    ex[e * NH + hh] = expf(a);         // max-shift skipped: alphas are O(0.1)
  }
}

// ---------------- per-dst-node gather aggregation + bias + relu --------------
__global__ void agg_kernel(const int* __restrict__ rowptr, const int* __restrict__ perm,
                           const int* __restrict__ src, const float* __restrict__ ex,
                           const float* __restrict__ h, const float* __restrict__ b,
                           float* __restrict__ g) {
  int n = blockIdx.x, t = threadIdx.x;
  __shared__ float sden[NH];
  int beg = rowptr[n], end = rowptr[n + 1];
  if (t < NH) {
    float s = 0.f;
    for (int j = beg; j < end; ++j) s += ex[perm[j] * NH + t];
    sden[t] = 1.0f / (s + 1e-16f);
  }
  __syncthreads();
  int head = t >> 5;
  float acc = 0.f;
  for (int j = beg; j < end; ++j) {
    int e = perm[j];
    int sn = src[e];
    float w = ex[e * NH + head] * sden[head];
    acc = fmaf(h[(size_t)sn * HC + t], w, acc);
  }
  float v = acc + b[t];
  g[(size_t)n * HC + t] = (v > 0.f) ? v : 0.f;
}

// ---------------- dense [N,256] @ [256,K] + bias -----------------------------
__global__ void lin_kernel(const float* __restrict__ gin, const float* __restrict__ W,
                           const float* __restrict__ b, float* __restrict__ xout,
                           int N_, int K) {
  int i = blockIdx.x * blockDim.x + threadIdx.x;
  if (i >= N_ * K) return;
  int n = i / K, k = i - n * K;
  float acc = b[k];
  const float* gr = gin + (size_t)n * HC;
  for (int j = 0; j < HC; ++j) acc = fmaf(gr[j], W[j * K + k], acc);
  xout[i] = acc;
}

// ---------------- classifier: sigmoid(sum(fu*fm)) ----------------------------
__global__ void clf_kernel(const int* __restrict__ eli, const float* __restrict__ ela,
                           const float* __restrict__ x2, const float* __restrict__ clfW,
                           const float* __restrict__ clfb, float* __restrict__ out, int L_) {
  int i = blockIdx.x * blockDim.x + threadIdx.x;
  if (i >= L_) return;
  int u = eli[i], m = eli[L_ + i];
  float fu[NH];
#pragma unroll
  for (int k = 0; k < NH; ++k) fu[k] = clfb[k];
#pragma unroll
  for (int j = 0; j < NH; ++j) {
    float xv = x2[u * NH + j];
#pragma unroll
    for (int k = 0; k < NH; ++k) fu[k] = fmaf(xv, clfW[j * NH + k], fu[k]);
  }
#pragma unroll
  for (int j = 0; j < NH; ++j) {
    float av = ela[i * NH + j];
#pragma unroll
    for (int k = 0; k < NH; ++k) fu[k] = fmaf(av, clfW[(NH + j) * NH + k], fu[k]);
  }
  float dot = 0.f;
#pragma unroll
  for (int k = 0; k < NH; ++k) dot += fu[k] * x2[m * NH + k];
  out[i] = 1.f / (1.f + expf(-dot));
}

extern "C" void kernel_launch(void* const* d_in, const int* in_sizes, int n_in,
                              void* d_out, int out_size, void* d_ws, size_t ws_size,
                              hipStream_t stream) {
  const int* node_ids   = (const int*)d_in[0];
  const int* edge_index = (const int*)d_in[1];
  const int* eli        = (const int*)d_in[2];
  // d_in[3] = topic (unused)
  const float* edge_attr = (const float*)d_in[4];
  const float* ela       = (const float*)d_in[5];
  const float* emb       = (const float*)d_in[6];
  const float* W1     = (const float*)d_in[7];
  const float* a_src1 = (const float*)d_in[8];
  const float* a_dst1 = (const float*)d_in[9];
  const float* We1    = (const float*)d_in[10];
  const float* a_e1   = (const float*)d_in[11];
  const float* b1     = (const float*)d_in[12];
  const float* lin1W  = (const float*)d_in[13];
  const float* lin1b  = (const float*)d_in[14];
  const float* W2     = (const float*)d_in[15];
  const float* a_src2 = (const float*)d_in[16];
  const float* a_dst2 = (const float*)d_in[17];
  const float* We2    = (const float*)d_in[18];
  const float* a_e2   = (const float*)d_in[19];
  const float* b2     = (const float*)d_in[20];
  const float* lin5W  = (const float*)d_in[21];
  const float* lin5b  = (const float*)d_in[22];
  const float* clfW   = (const float*)d_in[23];
  const float* clfb   = (const float*)d_in[24];

  const int N_ = in_sizes[0];
  const int E_ = in_sizes[1] / 2;
  const int L_ = in_sizes[2] / 2;
  const int* src  = edge_index;
  const int* dstp = edge_index + E_;

  char* p = (char*)d_ws;
  auto carve = [&](size_t bytes) -> char* {
    char* r = p;
    p += (bytes + 255) & ~(size_t)255;
    return r;
  };
  float* hbuf   = (float*)carve((size_t)N_ * HC * 4);   // 51.2 MB
  float* gbuf   = (float*)carve((size_t)N_ * HC * 4);   // 51.2 MB
  float* exbuf  = (float*)carve((size_t)E_ * NH * 4);   // 25.6 MB
  float* alsrc  = (float*)carve((size_t)N_ * NH * 4);
  float* aldst  = (float*)carve((size_t)N_ * NH * 4);
  float* x1b    = (float*)carve((size_t)N_ * FIN * 4);
  float* x2b    = (float*)carve((size_t)N_ * NH * 4);
  float* Mbuf   = (float*)carve(128 * 4);
  int*   cnt    = (int*)carve((size_t)N_ * 4);
  int*   rowptr = (int*)carve((size_t)(N_ + 1) * 4);
  int*   fill   = (int*)carve((size_t)N_ * 4);
  int*   perm   = (int*)carve((size_t)E_ * 4);

  hipMemsetAsync(cnt, 0, (size_t)N_ * 4, stream);
  int eb = (E_ + 255) / 256;
  count_kernel<<<eb, 256, 0, stream>>>(dstp, cnt, E_);
  scan_kernel<<<1, 1024, 0, stream>>>(cnt, rowptr, fill, N_, E_);
  scatter_kernel<<<eb, 256, 0, stream>>>(dstp, fill, perm, E_);
  fold_kernel<<<1, 128, 0, stream>>>(We1, a_e1, We2, a_e2, Mbuf);

  // ---- layer 1 ----
  node_kernel<<<N_, 256, 0, stream>>>(emb, node_ids, nullptr, W1, a_src1, a_dst1,
                                      hbuf, alsrc, aldst);
  edge_kernel<<<eb, 256, 0, stream>>>(src, dstp, edge_attr, Mbuf, alsrc, aldst, exbuf, E_);
  agg_kernel<<<N_, 256, 0, stream>>>(rowptr, perm, src, exbuf, hbuf, b1, gbuf);
  lin_kernel<<<(N_ * FIN + 255) / 256, 256, 0, stream>>>(gbuf, lin1W, lin1b, x1b, N_, FIN);

  // ---- layer 2 ----
  node_kernel<<<N_, 256, 0, stream>>>(nullptr, nullptr, x1b, W2, a_src2, a_dst2,
                                      hbuf, alsrc, aldst);
  edge_kernel<<<eb, 256, 0, stream>>>(src, dstp, edge_attr, Mbuf + 64, alsrc, aldst, exbuf, E_);
  agg_kernel<<<N_, 256, 0, stream>>>(rowptr, perm, src, exbuf, hbuf, b2, gbuf);
  lin_kernel<<<(N_ * NH + 255) / 256, 256, 0, stream>>>(gbuf, lin5W, lin5b, x2b, N_, NH);

  // ---- classifier ----
  clf_kernel<<<(L_ + 255) / 256, 256, 0, stream>>>(eli, ela, x2b, clfW, clfb,
                                                   (float*)d_out, L_);
}

// Round 3
// 877.613 us; speedup vs baseline: 1.5442x; 1.5442x over previous
//
#include <hip/hip_runtime.h>
#include <hip/hip_bf16.h>

#define HC  256   // H * C (heads * per-head channels)
#define FIN 32    // input feature dim of each GAT layer
#define NH  8     // heads

// ---------------- CSR build (dst is identical for both layers) ----------------
__global__ void count_kernel(const int* __restrict__ dst, int* __restrict__ cnt, int E_) {
  int e = blockIdx.x * blockDim.x + threadIdx.x;
  if (e < E_) atomicAdd(&cnt[dst[e]], 1);
}

__global__ void scan_kernel(const int* __restrict__ cnt, int* __restrict__ rowptr,
                            int* __restrict__ fill, int N_, int E_) {
  __shared__ int part[1024];
  int t = threadIdx.x;
  int chunk = (N_ + 1023) / 1024;
  int lo = t * chunk, hi = lo + chunk;
  if (lo > N_) lo = N_;
  if (hi > N_) hi = N_;
  int s = 0;
  for (int i = lo; i < hi; ++i) s += cnt[i];
  part[t] = s;
  __syncthreads();
  if (t == 0) {
    int run = 0;
    for (int i = 0; i < 1024; ++i) { int v = part[i]; part[i] = run; run += v; }
  }
  __syncthreads();
  int run = part[t];
  for (int i = lo; i < hi; ++i) { rowptr[i] = run; fill[i] = run; run += cnt[i]; }
  if (t == 0) rowptr[N_] = E_;
}

// scatter edges into CSR order; also emit per-position src and dst arrays
__global__ void scatter_kernel(const int* __restrict__ src, const int* __restrict__ dst,
                               int* __restrict__ fill, int* __restrict__ perm,
                               int* __restrict__ srcs, int* __restrict__ dsts, int E_) {
  int e = blockIdx.x * blockDim.x + threadIdx.x;
  if (e < E_) {
    int d = dst[e];
    int pos = atomicAdd(&fill[d], 1);
    perm[pos] = e;
    srcs[pos] = src[e];
    dsts[pos] = d;
  }
}

// ---------------- fold We[8,256] x a_e[8,32] -> M[8,8] for both layers --------
__global__ void fold_kernel(const float* __restrict__ We1, const float* __restrict__ ae1,
                            const float* __restrict__ We2, const float* __restrict__ ae2,
                            float* __restrict__ M) {
  int t = threadIdx.x;             // 0..127
  const float* We = (t < 64) ? We1 : We2;
  const float* ae = (t < 64) ? ae1 : ae2;
  int i = t & 63;
  int k = i >> 3, hh = i & 7;
  float s = 0.f;
  for (int c = 0; c < FIN; ++c)
    s = fmaf(We[k * HC + hh * FIN + c], ae[hh * FIN + c], s);
  M[t] = s;                        // M[layer*64 + k*8 + hh]
}

// ---------------- h = x@W  (+ per-head attention logits) ---------------------
__global__ void node_kernel(const float* __restrict__ emb, const int* __restrict__ node_ids,
                            const float* __restrict__ xin,
                            const float* __restrict__ W,
                            const float* __restrict__ a_src, const float* __restrict__ a_dst,
                            float* __restrict__ h, float* __restrict__ alsrc,
                            float* __restrict__ aldst) {
  int n = blockIdx.x, t = threadIdx.x;
  __shared__ float xs[FIN];
  __shared__ float red[HC];
  if (t < FIN) {
    if (node_ids) xs[t] = emb[(size_t)node_ids[n] * FIN + t];
    else          xs[t] = xin[n * FIN + t];
  }
  __syncthreads();
  float acc = 0.f;
#pragma unroll
  for (int k = 0; k < FIN; ++k) acc = fmaf(xs[k], W[k * HC + t], acc);
  h[(size_t)n * HC + t] = acc;

  red[t] = acc * a_src[t];
  __syncthreads();
  if (t < NH) {
    float s = 0.f;
    for (int c = 0; c < FIN; ++c) s += red[t * FIN + c];
    alsrc[n * NH + t] = s;
  }
  __syncthreads();
  red[t] = acc * a_dst[t];
  __syncthreads();
  if (t < NH) {
    float s = 0.f;
    for (int c = 0; c < FIN; ++c) s += red[t * FIN + c];
    aldst[n * NH + t] = s;
  }
}

// ---------------- per-CSR-position: ex = exp(leaky_relu(alpha)), coalesced out
__global__ void edge_kernel(const int* __restrict__ perm, const int* __restrict__ srcs,
                            const int* __restrict__ dsts,
                            const float* __restrict__ edge_attr, const float* __restrict__ M,
                            const float* __restrict__ alsrc, const float* __restrict__ aldst,
                            float* __restrict__ ex_s, int E_) {
  int j = blockIdx.x * blockDim.x + threadIdx.x;
  if (j >= E_) return;
  int e = perm[j];
  int s = srcs[j], d = dsts[j];
  const float4* eap = (const float4*)(edge_attr + (size_t)e * NH);
  float4 ea0 = eap[0], ea1 = eap[1];
  float ea[NH] = {ea0.x, ea0.y, ea0.z, ea0.w, ea1.x, ea1.y, ea1.z, ea1.w};
  const float4* asp = (const float4*)(alsrc + (size_t)s * NH);
  const float4* adp = (const float4*)(aldst + (size_t)d * NH);
  float4 as0 = asp[0], as1 = asp[1];
  float4 ad0 = adp[0], ad1 = adp[1];
  float als[NH] = {as0.x, as0.y, as0.z, as0.w, as1.x, as1.y, as1.z, as1.w};
  float ald[NH] = {ad0.x, ad0.y, ad0.z, ad0.w, ad1.x, ad1.y, ad1.z, ad1.w};
  float out[NH];
#pragma unroll
  for (int hh = 0; hh < NH; ++hh) {
    float al = 0.f;
#pragma unroll
    for (int k = 0; k < NH; ++k) al = fmaf(ea[k], M[k * NH + hh], al);
    float a = als[hh] + ald[hh] + al;
    a = (a >= 0.f) ? a : 0.2f * a;     // leaky_relu, slope 0.2
    out[hh] = expf(a);                 // max-shift skipped: alphas are O(0.1)
  }
  float4* exp4 = (float4*)(ex_s + (size_t)j * NH);
  exp4[0] = make_float4(out[0], out[1], out[2], out[3]);
  exp4[1] = make_float4(out[4], out[5], out[6], out[7]);
}

// ---------------- per-dst-node gather aggregation + bias + relu --------------
__global__ __launch_bounds__(256) void
agg_kernel(const int* __restrict__ rowptr, const int* __restrict__ srcs,
           const float* __restrict__ ex_s, const float* __restrict__ h,
           const float* __restrict__ b, float* __restrict__ g) {
  int n = blockIdx.x, t = threadIdx.x;
  __shared__ float red[256];
  __shared__ float sden[NH];
  int beg = rowptr[n], end = rowptr[n + 1];

  // phase 1: denominators — coalesced strided read over ex_s[beg*8 .. end*8)
  {
    float part = 0.f;
    for (int q = beg * NH + t; q < end * NH; q += 256) part += ex_s[q];
    red[t] = part;                 // head of this partial = t & 7 (256 % 8 == 0)
    __syncthreads();
    if (t < NH) {
      float s = 0.f;
#pragma unroll
      for (int i = 0; i < 32; ++i) s += red[t + NH * i];
      sden[t] = 1.0f / (s + 1e-16f);
    }
    __syncthreads();
  }

  int head = t >> 5;
  float rden = sden[head];
  float acc = 0.f;
  int j = beg;
  for (; j + 3 < end; j += 4) {
    int s0 = srcs[j], s1 = srcs[j + 1], s2 = srcs[j + 2], s3 = srcs[j + 3];
    float w0 = ex_s[(size_t)j * NH + head];
    float w1 = ex_s[(size_t)(j + 1) * NH + head];
    float w2 = ex_s[(size_t)(j + 2) * NH + head];
    float w3 = ex_s[(size_t)(j + 3) * NH + head];
    float h0 = h[(size_t)s0 * HC + t];
    float h1 = h[(size_t)s1 * HC + t];
    float h2 = h[(size_t)s2 * HC + t];
    float h3 = h[(size_t)s3 * HC + t];
    acc = fmaf(h0, w0, acc);
    acc = fmaf(h1, w1, acc);
    acc = fmaf(h2, w2, acc);
    acc = fmaf(h3, w3, acc);
  }
  for (; j < end; ++j) {
    int sn = srcs[j];
    float w = ex_s[(size_t)j * NH + head];
    acc = fmaf(h[(size_t)sn * HC + t], w, acc);
  }
  acc *= rden;
  float v = acc + b[t];
  g[(size_t)n * HC + t] = (v > 0.f) ? v : 0.f;
}

// ---------------- dense [N,256] @ [256,K] + bias -----------------------------
__global__ void lin_kernel(const float* __restrict__ gin, const float* __restrict__ W,
                           const float* __restrict__ b, float* __restrict__ xout,
                           int N_, int K) {
  int i = blockIdx.x * blockDim.x + threadIdx.x;
  if (i >= N_ * K) return;
  int n = i / K, k = i - n * K;
  float acc = b[k];
  const float* gr = gin + (size_t)n * HC;
  for (int j = 0; j < HC; ++j) acc = fmaf(gr[j], W[j * K + k], acc);
  xout[i] = acc;
}

// ---------------- classifier: sigmoid(sum(fu*fm)) ----------------------------
__global__ void clf_kernel(const int* __restrict__ eli, const float* __restrict__ ela,
                           const float* __restrict__ x2, const float* __restrict__ clfW,
                           const float* __restrict__ clfb, float* __restrict__ out, int L_) {
  int i = blockIdx.x * blockDim.x + threadIdx.x;
  if (i >= L_) return;
  int u = eli[i], m = eli[L_ + i];
  float fu[NH];
#pragma unroll
  for (int k = 0; k < NH; ++k) fu[k] = clfb[k];
#pragma unroll
  for (int j = 0; j < NH; ++j) {
    float xv = x2[u * NH + j];
#pragma unroll
    for (int k = 0; k < NH; ++k) fu[k] = fmaf(xv, clfW[j * NH + k], fu[k]);
  }
#pragma unroll
  for (int j = 0; j < NH; ++j) {
    float av = ela[i * NH + j];
#pragma unroll
    for (int k = 0; k < NH; ++k) fu[k] = fmaf(av, clfW[(NH + j) * NH + k], fu[k]);
  }
  float dot = 0.f;
#pragma unroll
  for (int k = 0; k < NH; ++k) dot += fu[k] * x2[m * NH + k];
  out[i] = 1.f / (1.f + expf(-dot));
}

extern "C" void kernel_launch(void* const* d_in, const int* in_sizes, int n_in,
                              void* d_out, int out_size, void* d_ws, size_t ws_size,
                              hipStream_t stream) {
  const int* node_ids   = (const int*)d_in[0];
  const int* edge_index = (const int*)d_in[1];
  const int* eli        = (const int*)d_in[2];
  // d_in[3] = topic (unused)
  const float* edge_attr = (const float*)d_in[4];
  const float* ela       = (const float*)d_in[5];
  const float* emb       = (const float*)d_in[6];
  const float* W1     = (const float*)d_in[7];
  const float* a_src1 = (const float*)d_in[8];
  const float* a_dst1 = (const float*)d_in[9];
  const float* We1    = (const float*)d_in[10];
  const float* a_e1   = (const float*)d_in[11];
  const float* b1     = (const float*)d_in[12];
  const float* lin1W  = (const float*)d_in[13];
  const float* lin1b  = (const float*)d_in[14];
  const float* W2     = (const float*)d_in[15];
  const float* a_src2 = (const float*)d_in[16];
  const float* a_dst2 = (const float*)d_in[17];
  const float* We2    = (const float*)d_in[18];
  const float* a_e2   = (const float*)d_in[19];
  const float* b2     = (const float*)d_in[20];
  const float* lin5W  = (const float*)d_in[21];
  const float* lin5b  = (const float*)d_in[22];
  const float* clfW   = (const float*)d_in[23];
  const float* clfb   = (const float*)d_in[24];

  const int N_ = in_sizes[0];
  const int E_ = in_sizes[1] / 2;
  const int L_ = in_sizes[2] / 2;
  const int* src  = edge_index;
  const int* dstp = edge_index + E_;

  char* p = (char*)d_ws;
  auto carve = [&](size_t bytes) -> char* {
    char* r = p;
    p += (bytes + 255) & ~(size_t)255;
    return r;
  };
  float* hbuf   = (float*)carve((size_t)N_ * HC * 4);   // 51.2 MB
  float* gbuf   = (float*)carve((size_t)N_ * HC * 4);   // 51.2 MB
  float* exbuf  = (float*)carve((size_t)E_ * NH * 4);   // 25.6 MB (CSR-sorted)
  float* alsrc  = (float*)carve((size_t)N_ * NH * 4);
  float* aldst  = (float*)carve((size_t)N_ * NH * 4);
  float* x1b    = (float*)carve((size_t)N_ * FIN * 4);
  float* x2b    = (float*)carve((size_t)N_ * NH * 4);
  float* Mbuf   = (float*)carve(128 * 4);
  int*   cnt    = (int*)carve((size_t)N_ * 4);
  int*   rowptr = (int*)carve((size_t)(N_ + 1) * 4);
  int*   fill   = (int*)carve((size_t)N_ * 4);
  int*   perm   = (int*)carve((size_t)E_ * 4);
  int*   srcs   = (int*)carve((size_t)E_ * 4);
  int*   dsts   = (int*)carve((size_t)E_ * 4);

  hipMemsetAsync(cnt, 0, (size_t)N_ * 4, stream);
  int eb = (E_ + 255) / 256;
  count_kernel<<<eb, 256, 0, stream>>>(dstp, cnt, E_);
  scan_kernel<<<1, 1024, 0, stream>>>(cnt, rowptr, fill, N_, E_);
  scatter_kernel<<<eb, 256, 0, stream>>>(src, dstp, fill, perm, srcs, dsts, E_);
  fold_kernel<<<1, 128, 0, stream>>>(We1, a_e1, We2, a_e2, Mbuf);

  // ---- layer 1 ----
  node_kernel<<<N_, 256, 0, stream>>>(emb, node_ids, nullptr, W1, a_src1, a_dst1,
                                      hbuf, alsrc, aldst);
  edge_kernel<<<eb, 256, 0, stream>>>(perm, srcs, dsts, edge_attr, Mbuf, alsrc, aldst,
                                      exbuf, E_);
  agg_kernel<<<N_, 256, 0, stream>>>(rowptr, srcs, exbuf, hbuf, b1, gbuf);
  lin_kernel<<<(N_ * FIN + 255) / 256, 256, 0, stream>>>(gbuf, lin1W, lin1b, x1b, N_, FIN);

  // ---- layer 2 ----
  node_kernel<<<N_, 256, 0, stream>>>(nullptr, nullptr, x1b, W2, a_src2, a_dst2,
                                      hbuf, alsrc, aldst);
  edge_kernel<<<eb, 256, 0, stream>>>(perm, srcs, dsts, edge_attr, Mbuf + 64, alsrc, aldst,
                                      exbuf, E_);
  agg_kernel<<<N_, 256, 0, stream>>>(rowptr, srcs, exbuf, hbuf, b2, gbuf);
  lin_kernel<<<(N_ * NH + 255) / 256, 256, 0, stream>>>(gbuf, lin5W, lin5b, x2b, N_, NH);

  // ---- classifier ----
  clf_kernel<<<(L_ + 255) / 256, 256, 0, stream>>>(eli, ela, x2b, clfW, clfb,
                                                   (float*)d_out, L_);
}

// Round 4
// 790.508 us; speedup vs baseline: 1.7144x; 1.1102x over previous
//
#include <hip/hip_runtime.h>
#include <hip/hip_bf16.h>

#define HC  256   // H * C (heads * per-head channels)
#define FIN 32    // input feature dim of each GAT layer
#define NH  8     // heads

typedef __hip_bfloat16 bf16;

// ---------------- CSR build (dst is identical for both layers) ----------------
__global__ void count_kernel(const int* __restrict__ dst, int* __restrict__ cnt, int E_) {
  int e = blockIdx.x * blockDim.x + threadIdx.x;
  if (e < E_) atomicAdd(&cnt[dst[e]], 1);
}

__global__ void scan_kernel(const int* __restrict__ cnt, int* __restrict__ rowptr,
                            int* __restrict__ fill, int N_, int E_) {
  __shared__ int part[1024];
  int t = threadIdx.x;
  int chunk = (N_ + 1023) / 1024;
  int lo = t * chunk, hi = lo + chunk;
  if (lo > N_) lo = N_;
  if (hi > N_) hi = N_;
  int s = 0;
  for (int i = lo; i < hi; ++i) s += cnt[i];
  part[t] = s;
  __syncthreads();
  if (t == 0) {
    int run = 0;
    for (int i = 0; i < 1024; ++i) { int v = part[i]; part[i] = run; run += v; }
  }
  __syncthreads();
  int run = part[t];
  for (int i = lo; i < hi; ++i) { rowptr[i] = run; fill[i] = run; run += cnt[i]; }
  if (t == 0) rowptr[N_] = E_;
}

// scatter edges into CSR order; also emit per-position src and dst arrays
__global__ void scatter_kernel(const int* __restrict__ src, const int* __restrict__ dst,
                               int* __restrict__ fill, int* __restrict__ perm,
                               int* __restrict__ srcs, int* __restrict__ dsts, int E_) {
  int e = blockIdx.x * blockDim.x + threadIdx.x;
  if (e < E_) {
    int d = dst[e];
    int pos = atomicAdd(&fill[d], 1);
    perm[pos] = e;
    srcs[pos] = src[e];
    dsts[pos] = d;
  }
}

// ---------------- fold We[8,256] x a_e[8,32] -> M[8,8] for both layers --------
__global__ void fold_kernel(const float* __restrict__ We1, const float* __restrict__ ae1,
                            const float* __restrict__ We2, const float* __restrict__ ae2,
                            float* __restrict__ M) {
  int t = threadIdx.x;             // 0..127
  const float* We = (t < 64) ? We1 : We2;
  const float* ae = (t < 64) ? ae1 : ae2;
  int i = t & 63;
  int k = i >> 3, hh = i & 7;
  float s = 0.f;
  for (int c = 0; c < FIN; ++c)
    s = fmaf(We[k * HC + hh * FIN + c], ae[hh * FIN + c], s);
  M[t] = s;                        // M[layer*64 + k*8 + hh]
}

// ---------------- h = x@W (bf16 store) + per-head attention logits -----------
__global__ void node_kernel(const float* __restrict__ emb, const int* __restrict__ node_ids,
                            const float* __restrict__ xin,
                            const float* __restrict__ W,
                            const float* __restrict__ a_src, const float* __restrict__ a_dst,
                            bf16* __restrict__ h, float* __restrict__ alsrc,
                            float* __restrict__ aldst) {
  int n = blockIdx.x, t = threadIdx.x;
  __shared__ float xs[FIN];
  __shared__ float red[HC];
  if (t < FIN) {
    if (node_ids) xs[t] = emb[(size_t)node_ids[n] * FIN + t];
    else          xs[t] = xin[n * FIN + t];
  }
  __syncthreads();
  float acc = 0.f;
#pragma unroll
  for (int k = 0; k < FIN; ++k) acc = fmaf(xs[k], W[k * HC + t], acc);
  h[(size_t)n * HC + t] = __float2bfloat16(acc);

  red[t] = acc * a_src[t];
  __syncthreads();
  if (t < NH) {
    float s = 0.f;
    for (int c = 0; c < FIN; ++c) s += red[t * FIN + c];
    alsrc[n * NH + t] = s;
  }
  __syncthreads();
  red[t] = acc * a_dst[t];
  __syncthreads();
  if (t < NH) {
    float s = 0.f;
    for (int c = 0; c < FIN; ++c) s += red[t * FIN + c];
    aldst[n * NH + t] = s;
  }
}

// ---------------- per-CSR-position: ex = exp(leaky_relu(alpha)), coalesced out
__global__ void edge_kernel(const int* __restrict__ perm, const int* __restrict__ srcs,
                            const int* __restrict__ dsts,
                            const float* __restrict__ edge_attr, const float* __restrict__ M,
                            const float* __restrict__ alsrc, const float* __restrict__ aldst,
                            float* __restrict__ ex_s, int E_) {
  int j = blockIdx.x * blockDim.x + threadIdx.x;
  if (j >= E_) return;
  int e = perm[j];
  int s = srcs[j], d = dsts[j];
  const float4* eap = (const float4*)(edge_attr + (size_t)e * NH);
  float4 ea0 = eap[0], ea1 = eap[1];
  float ea[NH] = {ea0.x, ea0.y, ea0.z, ea0.w, ea1.x, ea1.y, ea1.z, ea1.w};
  const float4* asp = (const float4*)(alsrc + (size_t)s * NH);
  const float4* adp = (const float4*)(aldst + (size_t)d * NH);
  float4 as0 = asp[0], as1 = asp[1];
  float4 ad0 = adp[0], ad1 = adp[1];
  float als[NH] = {as0.x, as0.y, as0.z, as0.w, as1.x, as1.y, as1.z, as1.w};
  float ald[NH] = {ad0.x, ad0.y, ad0.z, ad0.w, ad1.x, ad1.y, ad1.z, ad1.w};
  float out[NH];
#pragma unroll
  for (int hh = 0; hh < NH; ++hh) {
    float al = 0.f;
#pragma unroll
    for (int k = 0; k < NH; ++k) al = fmaf(ea[k], M[k * NH + hh], al);
    float a = als[hh] + ald[hh] + al;
    a = (a >= 0.f) ? a : 0.2f * a;     // leaky_relu, slope 0.2
    out[hh] = expf(a);                 // max-shift skipped: alphas are O(0.1)
  }
  float4* exp4 = (float4*)(ex_s + (size_t)j * NH);
  exp4[0] = make_float4(out[0], out[1], out[2], out[3]);
  exp4[1] = make_float4(out[4], out[5], out[6], out[7]);
}

// ------- per-dst-node: softmax-weighted gather + bias + relu + fused lin -----
// g (256 wide, in LDS) -> xout[n, 0..K) = relu(g) @ Wlin + blin
template <int K, int LOG2K>
__global__ __launch_bounds__(256) void
agg_lin_kernel(const int* __restrict__ rowptr, const int* __restrict__ srcs,
               const float* __restrict__ ex_s, const bf16* __restrict__ h,
               const float* __restrict__ b,
               const float* __restrict__ Wlin, const float* __restrict__ blin,
               float* __restrict__ xout) {
  int n = blockIdx.x, t = threadIdx.x;
  __shared__ float red[256];
  __shared__ float gs[256];
  __shared__ float sden[NH];
  int beg = rowptr[n], end = rowptr[n + 1];

  // phase 1: denominators — coalesced strided read over ex_s[beg*8 .. end*8)
  {
    float part = 0.f;
    for (int q = beg * NH + t; q < end * NH; q += 256) part += ex_s[q];
    red[t] = part;                 // head of this partial = t & 7 (256 % 8 == 0)
    __syncthreads();
    if (t < NH) {
      float s = 0.f;
#pragma unroll
      for (int i = 0; i < 32; ++i) s += red[t + NH * i];
      sden[t] = 1.0f / (s + 1e-16f);
    }
    __syncthreads();
  }

  // phase 2: weighted gather of h rows (bf16), 4-wide MLP unroll
  int head = t >> 5;
  float rden = sden[head];
  float acc = 0.f;
  int j = beg;
  for (; j + 3 < end; j += 4) {
    int s0 = srcs[j], s1 = srcs[j + 1], s2 = srcs[j + 2], s3 = srcs[j + 3];
    float w0 = ex_s[(size_t)j * NH + head];
    float w1 = ex_s[(size_t)(j + 1) * NH + head];
    float w2 = ex_s[(size_t)(j + 2) * NH + head];
    float w3 = ex_s[(size_t)(j + 3) * NH + head];
    float h0 = __bfloat162float(h[(size_t)s0 * HC + t]);
    float h1 = __bfloat162float(h[(size_t)s1 * HC + t]);
    float h2 = __bfloat162float(h[(size_t)s2 * HC + t]);
    float h3 = __bfloat162float(h[(size_t)s3 * HC + t]);
    acc = fmaf(h0, w0, acc);
    acc = fmaf(h1, w1, acc);
    acc = fmaf(h2, w2, acc);
    acc = fmaf(h3, w3, acc);
  }
  for (; j < end; ++j) {
    int sn = srcs[j];
    float w = ex_s[(size_t)j * NH + head];
    acc = fmaf(__bfloat162float(h[(size_t)sn * HC + t]), w, acc);
  }
  float v = acc * rden + b[t];
  gs[t] = (v > 0.f) ? v : 0.f;       // g row in LDS
  __syncthreads();

  // phase 3: fused dense  xout[n,k] = sum_j gs[j] * Wlin[j*K+k] + blin[k]
  {
    int k = t & (K - 1), r = t >> LOG2K;   // 256/K groups, chunk length K
    float part = 0.f;
#pragma unroll
    for (int i = 0; i < K; ++i) {
      int jj = r * K + i;
      part = fmaf(gs[jj], Wlin[jj * K + k], part);
    }
    red[t] = part;
    __syncthreads();
    if (t < K) {
      float s = blin[t];
#pragma unroll
      for (int r2 = 0; r2 < 256 / K; ++r2) s += red[r2 * K + t];
      xout[(size_t)n * K + t] = s;
    }
  }
}

// ---------------- classifier: sigmoid(sum(fu*fm)) ----------------------------
__global__ void clf_kernel(const int* __restrict__ eli, const float* __restrict__ ela,
                           const float* __restrict__ x2, const float* __restrict__ clfW,
                           const float* __restrict__ clfb, float* __restrict__ out, int L_) {
  int i = blockIdx.x * blockDim.x + threadIdx.x;
  if (i >= L_) return;
  int u = eli[i], m = eli[L_ + i];
  float fu[NH];
#pragma unroll
  for (int k = 0; k < NH; ++k) fu[k] = clfb[k];
#pragma unroll
  for (int j = 0; j < NH; ++j) {
    float xv = x2[u * NH + j];
#pragma unroll
    for (int k = 0; k < NH; ++k) fu[k] = fmaf(xv, clfW[j * NH + k], fu[k]);
  }
#pragma unroll
  for (int j = 0; j < NH; ++j) {
    float av = ela[i * NH + j];
#pragma unroll
    for (int k = 0; k < NH; ++k) fu[k] = fmaf(av, clfW[(NH + j) * NH + k], fu[k]);
  }
  float dot = 0.f;
#pragma unroll
  for (int k = 0; k < NH; ++k) dot += fu[k] * x2[m * NH + k];
  out[i] = 1.f / (1.f + expf(-dot));
}

extern "C" void kernel_launch(void* const* d_in, const int* in_sizes, int n_in,
                              void* d_out, int out_size, void* d_ws, size_t ws_size,
                              hipStream_t stream) {
  const int* node_ids   = (const int*)d_in[0];
  const int* edge_index = (const int*)d_in[1];
  const int* eli        = (const int*)d_in[2];
  // d_in[3] = topic (unused)
  const float* edge_attr = (const float*)d_in[4];
  const float* ela       = (const float*)d_in[5];
  const float* emb       = (const float*)d_in[6];
  const float* W1     = (const float*)d_in[7];
  const float* a_src1 = (const float*)d_in[8];
  const float* a_dst1 = (const float*)d_in[9];
  const float* We1    = (const float*)d_in[10];
  const float* a_e1   = (const float*)d_in[11];
  const float* b1     = (const float*)d_in[12];
  const float* lin1W  = (const float*)d_in[13];
  const float* lin1b  = (const float*)d_in[14];
  const float* W2     = (const float*)d_in[15];
  const float* a_src2 = (const float*)d_in[16];
  const float* a_dst2 = (const float*)d_in[17];
  const float* We2    = (const float*)d_in[18];
  const float* a_e2   = (const float*)d_in[19];
  const float* b2     = (const float*)d_in[20];
  const float* lin5W  = (const float*)d_in[21];
  const float* lin5b  = (const float*)d_in[22];
  const float* clfW   = (const float*)d_in[23];
  const float* clfb   = (const float*)d_in[24];

  const int N_ = in_sizes[0];
  const int E_ = in_sizes[1] / 2;
  const int L_ = in_sizes[2] / 2;
  const int* src  = edge_index;
  const int* dstp = edge_index + E_;

  char* p = (char*)d_ws;
  auto carve = [&](size_t bytes) -> char* {
    char* r = p;
    p += (bytes + 255) & ~(size_t)255;
    return r;
  };
  bf16*  hbuf   = (bf16*)carve((size_t)N_ * HC * 2);    // 25.6 MB (bf16)
  float* exbuf  = (float*)carve((size_t)E_ * NH * 4);   // 25.6 MB (CSR-sorted)
  float* alsrc  = (float*)carve((size_t)N_ * NH * 4);
  float* aldst  = (float*)carve((size_t)N_ * NH * 4);
  float* x1b    = (float*)carve((size_t)N_ * FIN * 4);
  float* x2b    = (float*)carve((size_t)N_ * NH * 4);
  float* Mbuf   = (float*)carve(128 * 4);
  int*   cnt    = (int*)carve((size_t)N_ * 4);
  int*   rowptr = (int*)carve((size_t)(N_ + 1) * 4);
  int*   fill   = (int*)carve((size_t)N_ * 4);
  int*   perm   = (int*)carve((size_t)E_ * 4);
  int*   srcs   = (int*)carve((size_t)E_ * 4);
  int*   dsts   = (int*)carve((size_t)E_ * 4);

  hipMemsetAsync(cnt, 0, (size_t)N_ * 4, stream);
  int eb = (E_ + 255) / 256;
  count_kernel<<<eb, 256, 0, stream>>>(dstp, cnt, E_);
  scan_kernel<<<1, 1024, 0, stream>>>(cnt, rowptr, fill, N_, E_);
  scatter_kernel<<<eb, 256, 0, stream>>>(src, dstp, fill, perm, srcs, dsts, E_);
  fold_kernel<<<1, 128, 0, stream>>>(We1, a_e1, We2, a_e2, Mbuf);

  // ---- layer 1 ----
  node_kernel<<<N_, 256, 0, stream>>>(emb, node_ids, nullptr, W1, a_src1, a_dst1,
                                      hbuf, alsrc, aldst);
  edge_kernel<<<eb, 256, 0, stream>>>(perm, srcs, dsts, edge_attr, Mbuf, alsrc, aldst,
                                      exbuf, E_);
  agg_lin_kernel<32, 5><<<N_, 256, 0, stream>>>(rowptr, srcs, exbuf, hbuf, b1,
                                                lin1W, lin1b, x1b);

  // ---- layer 2 ----
  node_kernel<<<N_, 256, 0, stream>>>(nullptr, nullptr, x1b, W2, a_src2, a_dst2,
                                      hbuf, alsrc, aldst);
  edge_kernel<<<eb, 256, 0, stream>>>(perm, srcs, dsts, edge_attr, Mbuf + 64, alsrc, aldst,
                                      exbuf, E_);
  agg_lin_kernel<8, 3><<<N_, 256, 0, stream>>>(rowptr, srcs, exbuf, hbuf, b2,
                                               lin5W, lin5b, x2b);

  // ---- classifier ----
  clf_kernel<<<(L_ + 255) / 256, 256, 0, stream>>>(eli, ela, x2b, clfW, clfb,
                                                   (float*)d_out, L_);
}